// Round 1
// baseline (1016.175 us; speedup 1.0000x reference)
//
#include <hip/hip_runtime.h>
#include <math.h>

namespace {
constexpr int kB = 2, kN = 2048, kDim = 256, kH = 8, kDH = 32;
constexpr int kBH = kB * kH;
constexpr int kRowsTotal = kB * kN;          // 4096
constexpr int PROJ_ROWS = 8;
constexpr int TI = 64;    // query rows per attention block
constexpr int TJ = 128;   // key tile
constexpr long kPlane = (long)kBH * kN * kDH;  // 1,048,576 floats per tensor
constexpr float kQScale = 0.17677669529663689f;  // 1/sqrt(32)
}

// ---------------------------------------------------------------------------
// QKV projection: complex linear. Block = 256 threads (one per output col),
// PROJ_ROWS rows per block. x rows staged in LDS (broadcast reads).
// Writes q,k,v in [bh][n][dh] layout; attention scale folded into q.
// ---------------------------------------------------------------------------
__global__ __launch_bounds__(256, 2) void proj_kernel(
    const float* __restrict__ xr_g, const float* __restrict__ xi_g,
    const float* __restrict__ wq_r, const float* __restrict__ wq_i,
    const float* __restrict__ wkv_r, const float* __restrict__ wkv_i,
    float* __restrict__ qr_g, float* __restrict__ qi_g,
    float* __restrict__ kr_g, float* __restrict__ ki_g,
    float* __restrict__ vr_g, float* __restrict__ vi_g)
{
    __shared__ float sxr[PROJ_ROWS][kDim];
    __shared__ float sxi[PROJ_ROWS][kDim];
    const int tid = threadIdx.x;
    const int row0 = blockIdx.x * PROJ_ROWS;   // row in [0, B*N)
    #pragma unroll
    for (int r = 0; r < PROJ_ROWS; ++r) {
        sxr[r][tid] = xr_g[(long)(row0 + r) * kDim + tid];
        sxi[r][tid] = xi_g[(long)(row0 + r) * kDim + tid];
    }
    __syncthreads();

    const int c = tid;
    float aqr[PROJ_ROWS] = {}, aqi[PROJ_ROWS] = {}, akr[PROJ_ROWS] = {},
          aki[PROJ_ROWS] = {}, avr[PROJ_ROWS] = {}, avi[PROJ_ROWS] = {};

    #pragma unroll 4
    for (int k = 0; k < kDim; ++k) {
        const float w0 = wq_r[k * kDim + c];
        const float w1 = wq_i[k * kDim + c];
        const float w2 = wkv_r[k * 2 * kDim + c];
        const float w3 = wkv_i[k * 2 * kDim + c];
        const float w4 = wkv_r[k * 2 * kDim + kDim + c];
        const float w5 = wkv_i[k * 2 * kDim + kDim + c];
        #pragma unroll
        for (int r = 0; r < PROJ_ROWS; ++r) {
            const float xr = sxr[r][k], xi = sxi[r][k];
            aqr[r] = fmaf(xr, w0, fmaf(-xi, w1, aqr[r]));
            aqi[r] = fmaf(xr, w1, fmaf( xi, w0, aqi[r]));
            akr[r] = fmaf(xr, w2, fmaf(-xi, w3, akr[r]));
            aki[r] = fmaf(xr, w3, fmaf( xi, w2, aki[r]));
            avr[r] = fmaf(xr, w4, fmaf(-xi, w5, avr[r]));
            avi[r] = fmaf(xr, w5, fmaf( xi, w4, avi[r]));
        }
    }

    const int h = c >> 5, d = c & 31;
    #pragma unroll
    for (int r = 0; r < PROJ_ROWS; ++r) {
        const int row = row0 + r;
        const int b = row >> 11;          // row / N
        const int n = row & (kN - 1);
        const long idx = (((long)(b * kH + h)) * kN + n) * kDH + d;
        qr_g[idx] = aqr[r] * kQScale;
        qi_g[idx] = aqi[r] * kQScale;
        kr_g[idx] = akr[r];
        ki_g[idx] = aki[r];
        vr_g[idx] = avr[r];
        vi_g[idx] = avi[r];
    }
}

// ---------------------------------------------------------------------------
// Attention. Block = 256 threads handles (bh, 64 query rows). Thread t owns
// row r = t&63 and j-part p = t>>6; all lanes of a wave share p -> K/V LDS
// reads are wave-broadcast. No max-subtraction needed (|logit| < ~15).
// Phase 1: per-replica denominators L_r. Phase 2: normalized accumulation
// with the sign-recombine: o = (alpha + i*gamma) * (vr + i*vi),
// alpha = p0 - p3, gamma = p1 + p2.
// ---------------------------------------------------------------------------
__global__ __launch_bounds__(256, 2) void attn_kernel(
    const float* __restrict__ qr_g, const float* __restrict__ qi_g,
    const float* __restrict__ kr_g, const float* __restrict__ ki_g,
    const float* __restrict__ vr_g, const float* __restrict__ vi_g,
    float* __restrict__ or_g, float* __restrict__ oi_g)
{
    __shared__ __align__(16) float smem[16384];   // 64 KiB
    float* sK = smem;             // [TJ][64] : kr(32) | ki(32)
    float* sV = smem + TJ * 64;   // [TJ][64] : vr(32) | vi(32)

    const int tid = threadIdx.x;
    const int r = tid & 63;
    const int p = tid >> 6;
    const int bh = blockIdx.y;
    const int i0 = blockIdx.x * TI;
    const long base = (long)bh * kN * kDH;

    // q fragment in registers (scale already folded in)
    float4 q_r[8], q_i[8];
    {
        const float* pr = qr_g + base + (long)(i0 + r) * kDH;
        const float* pi = qi_g + base + (long)(i0 + r) * kDH;
        #pragma unroll
        for (int dd = 0; dd < 8; ++dd) {
            q_r[dd] = *(const float4*)(pr + dd * 4);
            q_i[dd] = *(const float4*)(pi + dd * 4);
        }
    }

    const float* kb_r = kr_g + base;
    const float* kb_i = ki_g + base;
    const float* vb_r = vr_g + base;
    const float* vb_i = vi_g + base;

    // ---- phase 1: denominators ----
    float L0 = 0.f, L1 = 0.f, L2 = 0.f, L3 = 0.f;
    for (int jt = 0; jt < kN; jt += TJ) {
        __syncthreads();
        for (int t = tid; t < TJ * 16; t += 256) {
            const int j = t >> 4;
            const int s = t & 15;
            const float* src = (s < 8) ? (kb_r + (long)(jt + j) * kDH + s * 4)
                                       : (kb_i + (long)(jt + j) * kDH + (s - 8) * 4);
            *(float4*)(sK + j * 64 + s * 4) = *(const float4*)src;
        }
        __syncthreads();
        for (int jj = 0; jj < TJ / 4; ++jj) {
            const int j = p * (TJ / 4) + jj;
            const float4* krow = (const float4*)(sK + j * 64);
            float s0 = 0.f, s1 = 0.f, s2 = 0.f, s3 = 0.f;
            #pragma unroll
            for (int dd = 0; dd < 8; ++dd) {
                const float4 a = q_r[dd], b = q_i[dd];
                const float4 x = krow[dd], y = krow[8 + dd];
                s0 = fmaf(a.w, x.w, fmaf(a.z, x.z, fmaf(a.y, x.y, fmaf(a.x, x.x, s0))));
                s1 = fmaf(a.w, y.w, fmaf(a.z, y.z, fmaf(a.y, y.y, fmaf(a.x, y.x, s1))));
                s2 = fmaf(b.w, x.w, fmaf(b.z, x.z, fmaf(b.y, x.y, fmaf(b.x, x.x, s2))));
                s3 = fmaf(b.w, y.w, fmaf(b.z, y.z, fmaf(b.y, y.y, fmaf(b.x, y.x, s3))));
            }
            L0 += __expf(s0); L1 += __expf(s1); L2 += __expf(s2); L3 += __expf(s3);
        }
    }

    // merge partial L over the 4 j-parts (reuse smem)
    __syncthreads();
    {
        float4* lb4 = (float4*)smem;     // [64][4]
        lb4[r * 4 + p] = make_float4(L0, L1, L2, L3);
    }
    __syncthreads();
    float c0, c1, c2, c3;
    {
        const float4* lb4 = (const float4*)smem;
        const float4 a = lb4[r * 4 + 0], b = lb4[r * 4 + 1];
        const float4 c = lb4[r * 4 + 2], d = lb4[r * 4 + 3];
        c0 = __logf(a.x + b.x + c.x + d.x);
        c1 = __logf(a.y + b.y + c.y + d.y);
        c2 = __logf(a.z + b.z + c.z + d.z);
        c3 = __logf(a.w + b.w + c.w + d.w);
    }

    // ---- phase 2: normalized AV accumulation ----
    float4 o_r[8], o_i[8];
    #pragma unroll
    for (int dd = 0; dd < 8; ++dd) {
        o_r[dd] = make_float4(0.f, 0.f, 0.f, 0.f);
        o_i[dd] = make_float4(0.f, 0.f, 0.f, 0.f);
    }
    for (int jt = 0; jt < kN; jt += TJ) {
        __syncthreads();
        for (int t = tid; t < TJ * 16; t += 256) {
            const int j = t >> 4;
            const int s = t & 15;
            const float* srcK = (s < 8) ? (kb_r + (long)(jt + j) * kDH + s * 4)
                                        : (kb_i + (long)(jt + j) * kDH + (s - 8) * 4);
            const float* srcV = (s < 8) ? (vb_r + (long)(jt + j) * kDH + s * 4)
                                        : (vb_i + (long)(jt + j) * kDH + (s - 8) * 4);
            *(float4*)(sK + j * 64 + s * 4) = *(const float4*)srcK;
            *(float4*)(sV + j * 64 + s * 4) = *(const float4*)srcV;
        }
        __syncthreads();
        for (int jj = 0; jj < TJ / 4; ++jj) {
            const int j = p * (TJ / 4) + jj;
            const float4* krow = (const float4*)(sK + j * 64);
            float s0 = 0.f, s1 = 0.f, s2 = 0.f, s3 = 0.f;
            #pragma unroll
            for (int dd = 0; dd < 8; ++dd) {
                const float4 a = q_r[dd], b = q_i[dd];
                const float4 x = krow[dd], y = krow[8 + dd];
                s0 = fmaf(a.w, x.w, fmaf(a.z, x.z, fmaf(a.y, x.y, fmaf(a.x, x.x, s0))));
                s1 = fmaf(a.w, y.w, fmaf(a.z, y.z, fmaf(a.y, y.y, fmaf(a.x, y.x, s1))));
                s2 = fmaf(b.w, x.w, fmaf(b.z, x.z, fmaf(b.y, x.y, fmaf(b.x, x.x, s2))));
                s3 = fmaf(b.w, y.w, fmaf(b.z, y.z, fmaf(b.y, y.y, fmaf(b.x, y.x, s3))));
            }
            const float al = __expf(s0 - c0) - __expf(s3 - c3);
            const float ga = __expf(s1 - c1) + __expf(s2 - c2);
            const float4* vrow = (const float4*)(sV + j * 64);
            #pragma unroll
            for (int dd = 0; dd < 8; ++dd) {
                const float4 x = vrow[dd], y = vrow[8 + dd];
                o_r[dd].x = fmaf(al, x.x, fmaf(-ga, y.x, o_r[dd].x));
                o_r[dd].y = fmaf(al, x.y, fmaf(-ga, y.y, o_r[dd].y));
                o_r[dd].z = fmaf(al, x.z, fmaf(-ga, y.z, o_r[dd].z));
                o_r[dd].w = fmaf(al, x.w, fmaf(-ga, y.w, o_r[dd].w));
                o_i[dd].x = fmaf(ga, x.x, fmaf(al, y.x, o_i[dd].x));
                o_i[dd].y = fmaf(ga, x.y, fmaf(al, y.y, o_i[dd].y));
                o_i[dd].z = fmaf(ga, x.z, fmaf(al, y.z, o_i[dd].z));
                o_i[dd].w = fmaf(ga, x.w, fmaf(al, y.w, o_i[dd].w));
            }
        }
    }

    // merge partial o over parts via LDS (reuse smem as [4][64][64])
    __syncthreads();
    {
        float4* ob = (float4*)(smem + ((p * 64 + r) * 64));
        #pragma unroll
        for (int dd = 0; dd < 8; ++dd) {
            ob[dd] = o_r[dd];
            ob[8 + dd] = o_i[dd];
        }
    }
    __syncthreads();
    {
        const int rr = tid >> 2;
        const int f0 = (tid & 3) * 16;
        #pragma unroll
        for (int f = 0; f < 16; ++f) {
            const int fd = f0 + f;
            const float v = smem[0 * 4096 + rr * 64 + fd] + smem[1 * 4096 + rr * 64 + fd]
                          + smem[2 * 4096 + rr * 64 + fd] + smem[3 * 4096 + rr * 64 + fd];
            if (fd < 32) or_g[base + (long)(i0 + rr) * kDH + fd] = v;
            else         oi_g[base + (long)(i0 + rr) * kDH + (fd - 32)] = v;
        }
    }
}

// ---------------------------------------------------------------------------
// Output projection: merge heads + complex linear; writes interleaved (r,i)
// as float2 -> perfectly coalesced stores.
// ---------------------------------------------------------------------------
__global__ __launch_bounds__(256, 2) void oproj_kernel(
    const float* __restrict__ or_g, const float* __restrict__ oi_g,
    const float* __restrict__ wo_r, const float* __restrict__ wo_i,
    float* __restrict__ out)
{
    __shared__ float smr[PROJ_ROWS][kDim];
    __shared__ float smi[PROJ_ROWS][kDim];
    const int tid = threadIdx.x;
    const int row0 = blockIdx.x * PROJ_ROWS;
    const int h = tid >> 5, d = tid & 31;
    #pragma unroll
    for (int r = 0; r < PROJ_ROWS; ++r) {
        const int row = row0 + r;
        const int b = row >> 11;
        const int n = row & (kN - 1);
        const long idx = (((long)(b * kH + h)) * kN + n) * kDH + d;
        smr[r][tid] = or_g[idx];
        smi[r][tid] = oi_g[idx];
    }
    __syncthreads();

    const int c = tid;
    float aor[PROJ_ROWS] = {}, aoi[PROJ_ROWS] = {};
    #pragma unroll 4
    for (int k = 0; k < kDim; ++k) {
        const float w0 = wo_r[k * kDim + c];
        const float w1 = wo_i[k * kDim + c];
        #pragma unroll
        for (int r = 0; r < PROJ_ROWS; ++r) {
            const float mr = smr[r][k], mi = smi[r][k];
            aor[r] = fmaf(mr, w0, fmaf(-mi, w1, aor[r]));
            aoi[r] = fmaf(mr, w1, fmaf( mi, w0, aoi[r]));
        }
    }
    float2* out2 = (float2*)out;
    #pragma unroll
    for (int r = 0; r < PROJ_ROWS; ++r) {
        out2[(long)(row0 + r) * kDim + c] = make_float2(aor[r], aoi[r]);
    }
}

extern "C" void kernel_launch(void* const* d_in, const int* in_sizes, int n_in,
                              void* d_out, int out_size, void* d_ws, size_t ws_size,
                              hipStream_t stream) {
    const float* xr    = (const float*)d_in[0];
    const float* xi    = (const float*)d_in[1];
    const float* wq_r  = (const float*)d_in[2];
    const float* wq_i  = (const float*)d_in[3];
    const float* wkv_r = (const float*)d_in[4];
    const float* wkv_i = (const float*)d_in[5];
    const float* wo_r  = (const float*)d_in[6];
    const float* wo_i  = (const float*)d_in[7];
    float* out = (float*)d_out;

    float* ws = (float*)d_ws;
    float* qr   = ws + 0 * kPlane;
    float* qi   = ws + 1 * kPlane;
    float* kr   = ws + 2 * kPlane;
    float* ki   = ws + 3 * kPlane;
    float* vr   = ws + 4 * kPlane;
    float* vi   = ws + 5 * kPlane;
    float* og_r = ws + 6 * kPlane;
    float* og_i = ws + 7 * kPlane;

    proj_kernel<<<kRowsTotal / PROJ_ROWS, 256, 0, stream>>>(
        xr, xi, wq_r, wq_i, wkv_r, wkv_i, qr, qi, kr, ki, vr, vi);
    attn_kernel<<<dim3(kN / TI, kBH), 256, 0, stream>>>(
        qr, qi, kr, ki, vr, vi, og_r, og_i);
    oproj_kernel<<<kRowsTotal / PROJ_ROWS, 256, 0, stream>>>(
        og_r, og_i, wo_r, wo_i, out);
}

// Round 2
// 317.772 us; speedup vs baseline: 3.1978x; 3.1978x over previous
//
#include <hip/hip_runtime.h>
#include <math.h>

namespace {
constexpr int kB = 2, kN = 2048, kDim = 256, kH = 8, kDH = 32;
constexpr int kBH = kB * kH;
constexpr int kRowsTotal = kB * kN;          // 4096
constexpr int PROJ_ROWS = 8;
constexpr long kPlane = (long)kBH * kN * kDH;  // 1,048,576 elems per tensor
// DH^-0.5 / ln2 folded into stored q so softmax weight = exp2(score)
constexpr float kQScaleL2 = 0.25506852552f;
}

typedef unsigned short u16;
typedef short short8 __attribute__((ext_vector_type(8)));
typedef float floatx16 __attribute__((ext_vector_type(16)));
#define MFMA_BF16(a, b, c) __builtin_amdgcn_mfma_f32_32x32x16_bf16(a, b, c, 0, 0, 0)

__device__ inline u16 bf16b(float x) {
    union { float f; unsigned u; } c; c.f = x;
    unsigned r = c.u + 0x7FFFu + ((c.u >> 16) & 1u);
    return (u16)(r >> 16);
}

// ---------------------------------------------------------------------------
// QKV projection (fp32 VALU compute, bf16 outputs). q gets log2-softmax scale.
// Layout of q/k/v: [bh][n][dh] bf16.
// ---------------------------------------------------------------------------
__global__ __launch_bounds__(256, 2) void proj_kernel(
    const float* __restrict__ xr_g, const float* __restrict__ xi_g,
    const float* __restrict__ wq_r, const float* __restrict__ wq_i,
    const float* __restrict__ wkv_r, const float* __restrict__ wkv_i,
    u16* __restrict__ qr_g, u16* __restrict__ qi_g,
    u16* __restrict__ kr_g, u16* __restrict__ ki_g,
    u16* __restrict__ vr_g, u16* __restrict__ vi_g)
{
    __shared__ float sxr[PROJ_ROWS][kDim];
    __shared__ float sxi[PROJ_ROWS][kDim];
    const int tid = threadIdx.x;
    const int row0 = blockIdx.x * PROJ_ROWS;
    #pragma unroll
    for (int r = 0; r < PROJ_ROWS; ++r) {
        sxr[r][tid] = xr_g[(long)(row0 + r) * kDim + tid];
        sxi[r][tid] = xi_g[(long)(row0 + r) * kDim + tid];
    }
    __syncthreads();

    const int c = tid;
    float aqr[PROJ_ROWS] = {}, aqi[PROJ_ROWS] = {}, akr[PROJ_ROWS] = {},
          aki[PROJ_ROWS] = {}, avr[PROJ_ROWS] = {}, avi[PROJ_ROWS] = {};

    #pragma unroll 4
    for (int k = 0; k < kDim; ++k) {
        const float w0 = wq_r[k * kDim + c];
        const float w1 = wq_i[k * kDim + c];
        const float w2 = wkv_r[k * 2 * kDim + c];
        const float w3 = wkv_i[k * 2 * kDim + c];
        const float w4 = wkv_r[k * 2 * kDim + kDim + c];
        const float w5 = wkv_i[k * 2 * kDim + kDim + c];
        #pragma unroll
        for (int r = 0; r < PROJ_ROWS; ++r) {
            const float xr = sxr[r][k], xi = sxi[r][k];
            aqr[r] = fmaf(xr, w0, fmaf(-xi, w1, aqr[r]));
            aqi[r] = fmaf(xr, w1, fmaf( xi, w0, aqi[r]));
            akr[r] = fmaf(xr, w2, fmaf(-xi, w3, akr[r]));
            aki[r] = fmaf(xr, w3, fmaf( xi, w2, aki[r]));
            avr[r] = fmaf(xr, w4, fmaf(-xi, w5, avr[r]));
            avi[r] = fmaf(xr, w5, fmaf( xi, w4, avi[r]));
        }
    }

    const int h = c >> 5, d = c & 31;
    #pragma unroll
    for (int r = 0; r < PROJ_ROWS; ++r) {
        const int row = row0 + r;
        const int b = row >> 11;
        const int n = row & (kN - 1);
        const long idx = (((long)(b * kH + h)) * kN + n) * kDH + d;
        qr_g[idx] = bf16b(aqr[r] * kQScaleL2);
        qi_g[idx] = bf16b(aqi[r] * kQScaleL2);
        kr_g[idx] = bf16b(akr[r]);
        ki_g[idx] = bf16b(aki[r]);
        vr_g[idx] = bf16b(avr[r]);
        vi_g[idx] = bf16b(avi[r]);
    }
}

// ---------------------------------------------------------------------------
// MFMA flash attention over the 4-replica complex structure.
// Block = (bh, 64 complex queries) -> 128 big rows (qr strips, qi strips),
// 4 waves x 32 rows. j-loop over 32-complex-key tiles (64 big cols).
// Single pass, unnormalized (scores bounded); per-replica L in registers.
// ---------------------------------------------------------------------------
__global__ __launch_bounds__(256, 2) void attn_kernel(
    const u16* __restrict__ qr_g, const u16* __restrict__ qi_g,
    const u16* __restrict__ kr_g, const u16* __restrict__ ki_g,
    const u16* __restrict__ vr_g, const u16* __restrict__ vi_g,
    float* __restrict__ or_g, float* __restrict__ oi_g)
{
    // LDS: sK [64 bigkey][40] bf16 | sV(transposed) [64 vcol][40] bf16 |
    //      sP per-wave [32 q][72] bf16 (overlaid by fp32 combine buffer)
    __shared__ __align__(16) unsigned char smem[5120 + 5120 + 18432];
    u16* sK = (u16*)smem;
    u16* sV = (u16*)(smem + 5120);
    u16* sPbase = (u16*)(smem + 10240);
    float* sC = (float*)(smem + 10240);

    const int tid = threadIdx.x;
    const int lane = tid & 63;
    const int w = tid >> 6;
    const int l31 = lane & 31;
    const int lh = lane >> 5;
    const int strip = w & 1;     // which 32-query strip
    const int qtype = w >> 1;    // 0 = qr rows, 1 = qi rows

    const int bh = blockIdx.y;
    const int i0 = blockIdx.x * 64;
    const long base = (long)bh * kN * kDH;

    // Q A-fragments (2 frags cover K=32), loaded once
    const u16* qg = (qtype ? qi_g : qr_g) + base;
    short8 qA0, qA1;
    {
        const u16* p = qg + (long)(i0 + strip * 32 + l31) * kDH + lh * 8;
        qA0 = *(const short8*)(p);
        qA1 = *(const short8*)(p + 16);
    }

    const u16* kgr = kr_g + base;
    const u16* kgi = ki_g + base;
    const u16* vgr = vr_g + base;
    const u16* vgi = vi_g + base;

    floatx16 UA0 = {0}, UA1 = {0}, UB0 = {0}, UB1 = {0};
    float La0[16], La1[16];
    #pragma unroll
    for (int r = 0; r < 16; ++r) { La0[r] = 0.f; La1[r] = 0.f; }

    u16* myP = sPbase + w * (32 * 72);
    const int krow = tid & 63, kdg = tid >> 6;       // K staging role
    const int vkey = tid & 31, vcg = tid >> 5;       // V staging role

    for (int jt = 0; jt < kN; jt += 32) {
        __syncthreads();
        // stage K tile: [bigkey 0..63][d 0..31], row pad to 40
        {
            const u16* src = ((krow < 32) ? kgr : kgi)
                           + (long)(jt + (krow & 31)) * kDH + kdg * 8;
            *(short8*)(sK + krow * 40 + kdg * 8) = *(const short8*)src;
        }
        // stage V transposed: sV[vcol][key], vcol 0..31 = vr d, 32..63 = vi d
        {
            const u16* src = ((vcg < 4) ? vgr : vgi)
                           + (long)(jt + vkey) * kDH + (vcg & 3) * 8;
            short8 vv = *(const short8*)src;
            const int c0 = vcg * 8;
            #pragma unroll
            for (int j = 0; j < 8; ++j) sV[(c0 + j) * 40 + vkey] = (u16)vv[j];
        }
        __syncthreads();

        // scores: S0 = q . kr^T (keys 0..31), S1 = q . ki^T
        floatx16 S0 = {0}, S1 = {0};
        {
            short8 b0 = *(const short8*)(sK + l31 * 40 + lh * 8);
            short8 b1 = *(const short8*)(sK + l31 * 40 + 16 + lh * 8);
            short8 b2 = *(const short8*)(sK + (32 + l31) * 40 + lh * 8);
            short8 b3 = *(const short8*)(sK + (32 + l31) * 40 + 16 + lh * 8);
            S0 = MFMA_BF16(qA0, b0, S0);
            S0 = MFMA_BF16(qA1, b1, S0);
            S1 = MFMA_BF16(qA0, b2, S1);
            S1 = MFMA_BF16(qA1, b3, S1);
        }

        // exp2, accumulate replica sums, write P (bf16) to own LDS strip
        #pragma unroll
        for (int r = 0; r < 16; ++r) {
            const int q = (r & 3) + 8 * (r >> 2) + 4 * lh;
            const float e0 = __builtin_amdgcn_exp2f(S0[r]);
            const float e1 = __builtin_amdgcn_exp2f(S1[r]);
            La0[r] += e0;
            La1[r] += e1;
            myP[q * 72 + l31] = bf16b(e0);
            myP[q * 72 + 32 + l31] = bf16b(e1);
        }

        // PV: U[32 x 128] via 8 MFMAs
        {
            const u16* pp = myP + l31 * 72 + lh * 8;
            short8 a0 = *(const short8*)(pp);
            short8 a1 = *(const short8*)(pp + 16);
            short8 a2 = *(const short8*)(pp + 32);
            short8 a3 = *(const short8*)(pp + 48);
            short8 v00 = *(const short8*)(sV + l31 * 40 + lh * 8);
            short8 v01 = *(const short8*)(sV + l31 * 40 + 16 + lh * 8);
            short8 v10 = *(const short8*)(sV + (32 + l31) * 40 + lh * 8);
            short8 v11 = *(const short8*)(sV + (32 + l31) * 40 + 16 + lh * 8);
            UA0 = MFMA_BF16(a0, v00, UA0);
            UA0 = MFMA_BF16(a1, v01, UA0);
            UA1 = MFMA_BF16(a0, v10, UA1);
            UA1 = MFMA_BF16(a1, v11, UA1);
            UB0 = MFMA_BF16(a2, v00, UB0);
            UB0 = MFMA_BF16(a3, v01, UB0);
            UB1 = MFMA_BF16(a2, v10, UB1);
            UB1 = MFMA_BF16(a3, v11, UB1);
        }
    }

    // butterfly-reduce L over the 32-lane (column) groups; each lane ends up
    // holding exactly the row sums its U regs need (same row formula).
    #pragma unroll
    for (int r = 0; r < 16; ++r) {
        float a = La0[r], b = La1[r];
        #pragma unroll
        for (int m = 1; m <= 16; m <<= 1) {
            a += __shfl_xor(a, m);
            b += __shfl_xor(b, m);
        }
        La0[r] = 1.f / a;
        La1[r] = 1.f / b;
    }

    // per-wave partial outputs (normalize + sign recombine)
    float po_r[16], po_i[16];
    #pragma unroll
    for (int r = 0; r < 16; ++r) {
        if (qtype == 0) {   // replicas 0 (tile0) and 1 (tile1)
            po_r[r] =  UA0[r] * La0[r] - UB1[r] * La1[r];
            po_i[r] =  UA1[r] * La0[r] + UB0[r] * La1[r];
        } else {            // replicas 2 (tile0) and 3 (tile1)
            po_r[r] = -UA1[r] * La0[r] - UB0[r] * La1[r];
            po_i[r] =  UA0[r] * La0[r] - UB1[r] * La1[r];
        }
    }

    __syncthreads();   // all PV reads of sP done; safe to overlay sC
    if (qtype == 1) {
        float* dst = sC + strip * (2 * 32 * 33);
        #pragma unroll
        for (int r = 0; r < 16; ++r) {
            const int q = (r & 3) + 8 * (r >> 2) + 4 * lh;
            dst[q * 33 + l31] = po_r[r];
            dst[32 * 33 + q * 33 + l31] = po_i[r];
        }
    }
    __syncthreads();
    if (qtype == 0) {
        const float* src = sC + strip * (2 * 32 * 33);
        float* outr = or_g + base + (long)(i0 + strip * 32) * kDH;
        float* outi = oi_g + base + (long)(i0 + strip * 32) * kDH;
        #pragma unroll
        for (int r = 0; r < 16; ++r) {
            const int q = (r & 3) + 8 * (r >> 2) + 4 * lh;
            outr[q * kDH + l31] = po_r[r] + src[q * 33 + l31];
            outi[q * kDH + l31] = po_i[r] + src[32 * 33 + q * 33 + l31];
        }
    }
}

// ---------------------------------------------------------------------------
// Output projection (unchanged, fp32): merge heads + complex linear.
// ---------------------------------------------------------------------------
__global__ __launch_bounds__(256, 2) void oproj_kernel(
    const float* __restrict__ or_g, const float* __restrict__ oi_g,
    const float* __restrict__ wo_r, const float* __restrict__ wo_i,
    float* __restrict__ out)
{
    __shared__ float smr[PROJ_ROWS][kDim];
    __shared__ float smi[PROJ_ROWS][kDim];
    const int tid = threadIdx.x;
    const int row0 = blockIdx.x * PROJ_ROWS;
    const int h = tid >> 5, d = tid & 31;
    #pragma unroll
    for (int r = 0; r < PROJ_ROWS; ++r) {
        const int row = row0 + r;
        const int b = row >> 11;
        const int n = row & (kN - 1);
        const long idx = (((long)(b * kH + h)) * kN + n) * kDH + d;
        smr[r][tid] = or_g[idx];
        smi[r][tid] = oi_g[idx];
    }
    __syncthreads();

    const int c = tid;
    float aor[PROJ_ROWS] = {}, aoi[PROJ_ROWS] = {};
    #pragma unroll 4
    for (int k = 0; k < kDim; ++k) {
        const float w0 = wo_r[k * kDim + c];
        const float w1 = wo_i[k * kDim + c];
        #pragma unroll
        for (int r = 0; r < PROJ_ROWS; ++r) {
            const float mr = smr[r][k], mi = smi[r][k];
            aor[r] = fmaf(mr, w0, fmaf(-mi, w1, aor[r]));
            aoi[r] = fmaf(mr, w1, fmaf( mi, w0, aoi[r]));
        }
    }
    float2* out2 = (float2*)out;
    #pragma unroll
    for (int r = 0; r < PROJ_ROWS; ++r) {
        out2[(long)(row0 + r) * kDim + c] = make_float2(aor[r], aoi[r]);
    }
}

extern "C" void kernel_launch(void* const* d_in, const int* in_sizes, int n_in,
                              void* d_out, int out_size, void* d_ws, size_t ws_size,
                              hipStream_t stream) {
    const float* xr    = (const float*)d_in[0];
    const float* xi    = (const float*)d_in[1];
    const float* wq_r  = (const float*)d_in[2];
    const float* wq_i  = (const float*)d_in[3];
    const float* wkv_r = (const float*)d_in[4];
    const float* wkv_i = (const float*)d_in[5];
    const float* wo_r  = (const float*)d_in[6];
    const float* wo_i  = (const float*)d_in[7];
    float* out = (float*)d_out;

    u16* ws16 = (u16*)d_ws;
    u16* qr = ws16 + 0 * kPlane;
    u16* qi = ws16 + 1 * kPlane;
    u16* kr = ws16 + 2 * kPlane;
    u16* ki = ws16 + 3 * kPlane;
    u16* vr = ws16 + 4 * kPlane;
    u16* vi = ws16 + 5 * kPlane;
    float* og_r = (float*)((char*)d_ws + 6 * kPlane * sizeof(u16));
    float* og_i = og_r + kPlane;

    proj_kernel<<<kRowsTotal / PROJ_ROWS, 256, 0, stream>>>(
        xr, xi, wq_r, wq_i, wkv_r, wkv_i, qr, qi, kr, ki, vr, vi);
    attn_kernel<<<dim3(kN / 64, kBH), 256, 0, stream>>>(
        qr, qi, kr, ki, vr, vi, og_r, og_i);
    oproj_kernel<<<kRowsTotal / PROJ_ROWS, 256, 0, stream>>>(
        og_r, og_i, wo_r, wo_i, out);
}

// Round 3
// 217.308 us; speedup vs baseline: 4.6762x; 1.4623x over previous
//
#include <hip/hip_runtime.h>
#include <math.h>

namespace {
constexpr int kB = 2, kN = 2048, kDim = 256, kH = 8, kDH = 32;
constexpr int kBH = kB * kH;
constexpr long kPlane = (long)kBH * kN * kDH;  // 1,048,576 elems per tensor
// DH^-0.5 / ln2 folded into stored q so softmax weight = exp2(score)
constexpr float kQScaleL2 = 0.25506852552f;
}

typedef unsigned short u16;
typedef short short8 __attribute__((ext_vector_type(8)));
typedef short short4v __attribute__((ext_vector_type(4)));
typedef float floatx16 __attribute__((ext_vector_type(16)));
#define MFMA_BF16(a, b, c) __builtin_amdgcn_mfma_f32_32x32x16_bf16(a, b, c, 0, 0, 0)

__device__ inline u16 bf16b(float x) {
    union { float f; unsigned u; } c; c.f = x;
    unsigned r = c.u + 0x7FFFu + ((c.u >> 16) & 1u);
    return (u16)(r >> 16);
}

// ---------------------------------------------------------------------------
// Build doubled/transposed bf16 weight matrices:
//   Wbig^T [1536 cols][512 k]: col groups of 256 = {q_r,q_i,k_r,k_i,v_r,v_i};
//     k<256 rows = xr part, k>=256 = xi part, complex signs baked in,
//     kQScaleL2 folded into q columns.
//   WoT [512 cols][512 k]: cols 0..255 out_r, 256..511 out_i.
// ---------------------------------------------------------------------------
__global__ __launch_bounds__(256, 2) void prep_w(
    const float* __restrict__ wq_r, const float* __restrict__ wq_i,
    const float* __restrict__ wkv_r, const float* __restrict__ wkv_i,
    const float* __restrict__ wo_r, const float* __restrict__ wo_i,
    u16* __restrict__ Wbig, u16* __restrict__ WoT)
{
    const long base = ((long)blockIdx.x * 256 + threadIdx.x) * 4;
    if (base < 786432) {
        const int c = (int)(base >> 9);
        const int k = (int)(base & 511);
        const int g = c >> 8, d = c & 255;
        const bool hi = k >= 256;
        const int k2 = hi ? k - 256 : k;
        const float* src;
        float sgn = 1.f;
        int col, stride;
        if (g < 2) {
            stride = 256; col = d;
            if (g == 0) { src = hi ? wq_i : wq_r; if (hi) sgn = -1.f; }
            else        { src = hi ? wq_r : wq_i; }
            sgn *= kQScaleL2;
        } else {
            stride = 512;
            col = (g >= 4) ? d + 256 : d;
            if ((g & 1) == 0) { src = hi ? wkv_i : wkv_r; if (hi) sgn = -1.f; }
            else              { src = hi ? wkv_r : wkv_i; }
        }
        short4v v;
        #pragma unroll
        for (int j = 0; j < 4; ++j)
            v[j] = (short)bf16b(src[(long)(k2 + j) * stride + col] * sgn);
        *(short4v*)(Wbig + base) = v;
    } else {
        const long o = base - 786432;
        const int c = (int)(o >> 9);
        const int k = (int)(o & 511);
        const bool hi = k >= 256;
        const int k2 = hi ? k - 256 : k;
        const float* src;
        float sgn = 1.f;
        int col;
        if (c < 256) { col = c;       src = hi ? wo_i : wo_r; if (hi) sgn = -1.f; }
        else         { col = c - 256; src = hi ? wo_r : wo_i; }
        short4v v;
        #pragma unroll
        for (int j = 0; j < 4; ++j)
            v[j] = (short)bf16b(src[(long)(k2 + j) * 256 + col] * sgn);
        *(short4v*)(WoT + o) = v;
    }
}

// ---------------------------------------------------------------------------
// QKV projection as bf16 MFMA GEMM: [4096 x 512] @ [512 x 1536].
// A = (xr|xi) fp32, converted to bf16 during LDS staging. B = Wbig^T.
// Epilogue scatters into 6 bf16 planes in [bh][n][dh] layout.
// Tile 128x128, BK=32, 4 waves each computing a 64x64 quadrant.
// ---------------------------------------------------------------------------
__global__ __launch_bounds__(256, 2) void gemm_proj(
    const float* __restrict__ xr_g, const float* __restrict__ xi_g,
    const u16* __restrict__ BT,
    u16* __restrict__ qr, u16* __restrict__ qi, u16* __restrict__ kr,
    u16* __restrict__ ki, u16* __restrict__ vr, u16* __restrict__ vi)
{
    __shared__ __align__(16) u16 sA[128 * 32];
    __shared__ __align__(16) u16 sB[128 * 32];
    const int tid = threadIdx.x;
    const int lane = tid & 63, l31 = lane & 31, lh = lane >> 5;
    const int w = tid >> 6, wrow = w & 1, wcol = w >> 1;
    const int srow = tid >> 2, sseg = tid & 3;
    const int n0 = blockIdx.x * 128, m0 = blockIdx.y * 128;

    floatx16 a00 = {0}, a01 = {0}, a10 = {0}, a11 = {0};

    for (int kt = 0; kt < 512; kt += 32) {
        __syncthreads();
        const float* xbase = (kt < 256) ? xr_g : xi_g;
        const int kc = (kt & 255) + sseg * 8;
        #pragma unroll
        for (int i = 0; i < 2; ++i) {
            const int r = srow + i * 64;
            {
                const float* src = xbase + (long)(m0 + r) * 256 + kc;
                const float4 f0 = *(const float4*)(src);
                const float4 f1 = *(const float4*)(src + 4);
                short8 v;
                v[0] = (short)bf16b(f0.x); v[1] = (short)bf16b(f0.y);
                v[2] = (short)bf16b(f0.z); v[3] = (short)bf16b(f0.w);
                v[4] = (short)bf16b(f1.x); v[5] = (short)bf16b(f1.y);
                v[6] = (short)bf16b(f1.z); v[7] = (short)bf16b(f1.w);
                *(short8*)(sA + r * 32 + sseg * 8) = v;
            }
            *(short8*)(sB + r * 32 + sseg * 8) =
                *(const short8*)(BT + (long)(n0 + r) * 512 + kt + sseg * 8);
        }
        __syncthreads();
        #pragma unroll
        for (int s = 0; s < 2; ++s) {
            const int ko = s * 16 + lh * 8;
            const short8 fa0 = *(const short8*)(sA + (wrow * 64 + l31) * 32 + ko);
            const short8 fa1 = *(const short8*)(sA + (wrow * 64 + 32 + l31) * 32 + ko);
            const short8 fb0 = *(const short8*)(sB + (wcol * 64 + l31) * 32 + ko);
            const short8 fb1 = *(const short8*)(sB + (wcol * 64 + 32 + l31) * 32 + ko);
            a00 = MFMA_BF16(fa0, fb0, a00);
            a01 = MFMA_BF16(fa0, fb1, a01);
            a10 = MFMA_BF16(fa1, fb0, a10);
            a11 = MFMA_BF16(fa1, fb1, a11);
        }
    }

    floatx16 accs[2][2] = {{a00, a01}, {a10, a11}};
    #pragma unroll
    for (int rt = 0; rt < 2; ++rt) {
        #pragma unroll
        for (int ct = 0; ct < 2; ++ct) {
            const int colb = n0 + wcol * 64 + ct * 32;
            const int g = colb >> 8;
            const int h = (colb & 255) >> 5;
            u16* pl = (g == 0) ? qr : (g == 1) ? qi : (g == 2) ? kr
                     : (g == 3) ? ki : (g == 4) ? vr : vi;
            #pragma unroll
            for (int reg = 0; reg < 16; ++reg) {
                const int row = m0 + wrow * 64 + rt * 32 + (reg & 3) + 8 * (reg >> 2) + 4 * lh;
                const int b = row >> 11, nn = row & 2047;
                pl[(((long)(b * 8 + h)) * 2048 + nn) * 32 + l31] = bf16b(accs[rt][ct][reg]);
            }
        }
    }
}

// ---------------------------------------------------------------------------
// MFMA flash attention (as R2), epilogue writes bf16 merged-head rows
// Xo[4096][512] = (mr | mi) for the oproj GEMM.
// ---------------------------------------------------------------------------
__global__ __launch_bounds__(256, 2) void attn_kernel(
    const u16* __restrict__ qr_g, const u16* __restrict__ qi_g,
    const u16* __restrict__ kr_g, const u16* __restrict__ ki_g,
    const u16* __restrict__ vr_g, const u16* __restrict__ vi_g,
    u16* __restrict__ xo)
{
    __shared__ __align__(16) unsigned char smem[5120 + 5120 + 18432];
    u16* sK = (u16*)smem;
    u16* sV = (u16*)(smem + 5120);
    u16* sPbase = (u16*)(smem + 10240);
    float* sC = (float*)(smem + 10240);

    const int tid = threadIdx.x;
    const int lane = tid & 63;
    const int w = tid >> 6;
    const int l31 = lane & 31;
    const int lh = lane >> 5;
    const int strip = w & 1;
    const int qtype = w >> 1;

    const int bh = blockIdx.y;
    const int i0 = blockIdx.x * 64;
    const long base = (long)bh * kN * kDH;

    const u16* qg = (qtype ? qi_g : qr_g) + base;
    short8 qA0, qA1;
    {
        const u16* p = qg + (long)(i0 + strip * 32 + l31) * kDH + lh * 8;
        qA0 = *(const short8*)(p);
        qA1 = *(const short8*)(p + 16);
    }

    const u16* kgr = kr_g + base;
    const u16* kgi = ki_g + base;
    const u16* vgr = vr_g + base;
    const u16* vgi = vi_g + base;

    floatx16 UA0 = {0}, UA1 = {0}, UB0 = {0}, UB1 = {0};
    float La0[16], La1[16];
    #pragma unroll
    for (int r = 0; r < 16; ++r) { La0[r] = 0.f; La1[r] = 0.f; }

    u16* myP = sPbase + w * (32 * 72);
    const int krow = tid & 63, kdg = tid >> 6;
    const int vkey = tid & 31, vcg = tid >> 5;

    for (int jt = 0; jt < kN; jt += 32) {
        __syncthreads();
        {
            const u16* src = ((krow < 32) ? kgr : kgi)
                           + (long)(jt + (krow & 31)) * kDH + kdg * 8;
            *(short8*)(sK + krow * 40 + kdg * 8) = *(const short8*)src;
        }
        {
            const u16* src = ((vcg < 4) ? vgr : vgi)
                           + (long)(jt + vkey) * kDH + (vcg & 3) * 8;
            short8 vv = *(const short8*)src;
            const int c0 = vcg * 8;
            #pragma unroll
            for (int j = 0; j < 8; ++j) sV[(c0 + j) * 40 + vkey] = (u16)vv[j];
        }
        __syncthreads();

        floatx16 S0 = {0}, S1 = {0};
        {
            short8 b0 = *(const short8*)(sK + l31 * 40 + lh * 8);
            short8 b1 = *(const short8*)(sK + l31 * 40 + 16 + lh * 8);
            short8 b2 = *(const short8*)(sK + (32 + l31) * 40 + lh * 8);
            short8 b3 = *(const short8*)(sK + (32 + l31) * 40 + 16 + lh * 8);
            S0 = MFMA_BF16(qA0, b0, S0);
            S0 = MFMA_BF16(qA1, b1, S0);
            S1 = MFMA_BF16(qA0, b2, S1);
            S1 = MFMA_BF16(qA1, b3, S1);
        }

        #pragma unroll
        for (int r = 0; r < 16; ++r) {
            const int q = (r & 3) + 8 * (r >> 2) + 4 * lh;
            const float e0 = __builtin_amdgcn_exp2f(S0[r]);
            const float e1 = __builtin_amdgcn_exp2f(S1[r]);
            La0[r] += e0;
            La1[r] += e1;
            myP[q * 72 + l31] = bf16b(e0);
            myP[q * 72 + 32 + l31] = bf16b(e1);
        }

        {
            const u16* pp = myP + l31 * 72 + lh * 8;
            short8 a0 = *(const short8*)(pp);
            short8 a1 = *(const short8*)(pp + 16);
            short8 a2 = *(const short8*)(pp + 32);
            short8 a3 = *(const short8*)(pp + 48);
            short8 v00 = *(const short8*)(sV + l31 * 40 + lh * 8);
            short8 v01 = *(const short8*)(sV + l31 * 40 + 16 + lh * 8);
            short8 v10 = *(const short8*)(sV + (32 + l31) * 40 + lh * 8);
            short8 v11 = *(const short8*)(sV + (32 + l31) * 40 + 16 + lh * 8);
            UA0 = MFMA_BF16(a0, v00, UA0);
            UA0 = MFMA_BF16(a1, v01, UA0);
            UA1 = MFMA_BF16(a0, v10, UA1);
            UA1 = MFMA_BF16(a1, v11, UA1);
            UB0 = MFMA_BF16(a2, v00, UB0);
            UB0 = MFMA_BF16(a3, v01, UB0);
            UB1 = MFMA_BF16(a2, v10, UB1);
            UB1 = MFMA_BF16(a3, v11, UB1);
        }
    }

    #pragma unroll
    for (int r = 0; r < 16; ++r) {
        float a = La0[r], b = La1[r];
        #pragma unroll
        for (int m = 1; m <= 16; m <<= 1) {
            a += __shfl_xor(a, m);
            b += __shfl_xor(b, m);
        }
        La0[r] = 1.f / a;
        La1[r] = 1.f / b;
    }

    float po_r[16], po_i[16];
    #pragma unroll
    for (int r = 0; r < 16; ++r) {
        if (qtype == 0) {
            po_r[r] =  UA0[r] * La0[r] - UB1[r] * La1[r];
            po_i[r] =  UA1[r] * La0[r] + UB0[r] * La1[r];
        } else {
            po_r[r] = -UA1[r] * La0[r] - UB0[r] * La1[r];
            po_i[r] =  UA0[r] * La0[r] - UB1[r] * La1[r];
        }
    }

    __syncthreads();
    if (qtype == 1) {
        float* dst = sC + strip * (2 * 32 * 33);
        #pragma unroll
        for (int r = 0; r < 16; ++r) {
            const int q = (r & 3) + 8 * (r >> 2) + 4 * lh;
            dst[q * 33 + l31] = po_r[r];
            dst[32 * 33 + q * 33 + l31] = po_i[r];
        }
    }
    __syncthreads();
    if (qtype == 0) {
        const float* src = sC + strip * (2 * 32 * 33);
        const int b = bh >> 3, h = bh & 7;
        u16* xrow = xo + ((long)(b * 2048 + i0 + strip * 32)) * 512 + h * 32;
        #pragma unroll
        for (int r = 0; r < 16; ++r) {
            const int q = (r & 3) + 8 * (r >> 2) + 4 * lh;
            xrow[(long)q * 512 + l31] = bf16b(po_r[r] + src[q * 33 + l31]);
            xrow[(long)q * 512 + 256 + l31] = bf16b(po_i[r] + src[32 * 33 + q * 33 + l31]);
        }
    }
}

// ---------------------------------------------------------------------------
// Output projection GEMM: Xo[4096 x 512] @ WoT^T -> out fp32 interleaved.
// ---------------------------------------------------------------------------
__global__ __launch_bounds__(256, 2) void gemm_oproj(
    const u16* __restrict__ Xo, const u16* __restrict__ BT, float* __restrict__ out)
{
    __shared__ __align__(16) u16 sA[128 * 32];
    __shared__ __align__(16) u16 sB[128 * 32];
    const int tid = threadIdx.x;
    const int lane = tid & 63, l31 = lane & 31, lh = lane >> 5;
    const int w = tid >> 6, wrow = w & 1, wcol = w >> 1;
    const int srow = tid >> 2, sseg = tid & 3;
    const int n0 = blockIdx.x * 128, m0 = blockIdx.y * 128;

    floatx16 a00 = {0}, a01 = {0}, a10 = {0}, a11 = {0};

    for (int kt = 0; kt < 512; kt += 32) {
        __syncthreads();
        #pragma unroll
        for (int i = 0; i < 2; ++i) {
            const int r = srow + i * 64;
            *(short8*)(sA + r * 32 + sseg * 8) =
                *(const short8*)(Xo + (long)(m0 + r) * 512 + kt + sseg * 8);
            *(short8*)(sB + r * 32 + sseg * 8) =
                *(const short8*)(BT + (long)(n0 + r) * 512 + kt + sseg * 8);
        }
        __syncthreads();
        #pragma unroll
        for (int s = 0; s < 2; ++s) {
            const int ko = s * 16 + lh * 8;
            const short8 fa0 = *(const short8*)(sA + (wrow * 64 + l31) * 32 + ko);
            const short8 fa1 = *(const short8*)(sA + (wrow * 64 + 32 + l31) * 32 + ko);
            const short8 fb0 = *(const short8*)(sB + (wcol * 64 + l31) * 32 + ko);
            const short8 fb1 = *(const short8*)(sB + (wcol * 64 + 32 + l31) * 32 + ko);
            a00 = MFMA_BF16(fa0, fb0, a00);
            a01 = MFMA_BF16(fa0, fb1, a01);
            a10 = MFMA_BF16(fa1, fb0, a10);
            a11 = MFMA_BF16(fa1, fb1, a11);
        }
    }

    floatx16 accs[2][2] = {{a00, a01}, {a10, a11}};
    #pragma unroll
    for (int rt = 0; rt < 2; ++rt) {
        #pragma unroll
        for (int ct = 0; ct < 2; ++ct) {
            const int colb = n0 + wcol * 64 + ct * 32;
            #pragma unroll
            for (int reg = 0; reg < 16; ++reg) {
                const int row = m0 + wrow * 64 + rt * 32 + (reg & 3) + 8 * (reg >> 2) + 4 * lh;
                const int col = colb + l31;
                const float val = accs[rt][ct][reg];
                if (colb < 256) out[(long)row * 512 + col * 2] = val;
                else            out[(long)row * 512 + (col - 256) * 2 + 1] = val;
            }
        }
    }
}

extern "C" void kernel_launch(void* const* d_in, const int* in_sizes, int n_in,
                              void* d_out, int out_size, void* d_ws, size_t ws_size,
                              hipStream_t stream) {
    const float* xr    = (const float*)d_in[0];
    const float* xi    = (const float*)d_in[1];
    const float* wq_r  = (const float*)d_in[2];
    const float* wq_i  = (const float*)d_in[3];
    const float* wkv_r = (const float*)d_in[4];
    const float* wkv_i = (const float*)d_in[5];
    const float* wo_r  = (const float*)d_in[6];
    const float* wo_i  = (const float*)d_in[7];
    float* out = (float*)d_out;

    u16* ws16 = (u16*)d_ws;
    u16* qr   = ws16 + 0 * kPlane;
    u16* qi   = ws16 + 1 * kPlane;
    u16* kr   = ws16 + 2 * kPlane;
    u16* ki   = ws16 + 3 * kPlane;
    u16* vr   = ws16 + 4 * kPlane;
    u16* vi   = ws16 + 5 * kPlane;
    u16* xo   = ws16 + 6 * kPlane;               // 2,097,152 elems
    u16* Wbig = ws16 + 8 * kPlane;               // 786,432 elems
    u16* WoT  = Wbig + 786432;                   // 262,144 elems

    prep_w<<<1024, 256, 0, stream>>>(wq_r, wq_i, wkv_r, wkv_i, wo_r, wo_i, Wbig, WoT);
    gemm_proj<<<dim3(12, 32), 256, 0, stream>>>(xr, xi, Wbig, qr, qi, kr, ki, vr, vi);
    attn_kernel<<<dim3(kN / 64, kBH), 256, 0, stream>>>(qr, qi, kr, ki, vr, vi, xo);
    gemm_oproj<<<dim3(4, 32), 256, 0, stream>>>(xo, WoT, out);
}

// Round 5
// 212.965 us; speedup vs baseline: 4.7716x; 1.0204x over previous
//
#include <hip/hip_runtime.h>
#include <math.h>

namespace {
constexpr int kB = 2, kN = 2048, kDim = 256, kH = 8, kDH = 32;
constexpr int kBH = kB * kH;
constexpr long kPlane = (long)kBH * kN * kDH;  // 1,048,576 elems per tensor
// DH^-0.5 / ln2 folded into stored q so softmax weight = exp2(score)
constexpr float kQScaleL2 = 0.25506852552f;
}

typedef unsigned short u16;
typedef short short8 __attribute__((ext_vector_type(8)));
typedef short short4v __attribute__((ext_vector_type(4)));
typedef float floatx16 __attribute__((ext_vector_type(16)));
#define MFMA_BF16(a, b, c) __builtin_amdgcn_mfma_f32_32x32x16_bf16(a, b, c, 0, 0, 0)

__device__ inline u16 bf16b(float x) {
    union { float f; unsigned u; } c; c.f = x;
    unsigned r = c.u + 0x7FFFu + ((c.u >> 16) & 1u);
    return (u16)(r >> 16);
}
__device__ inline unsigned pack2(float x, float y) {
    return (unsigned)bf16b(x) | ((unsigned)bf16b(y) << 16);
}

// ---------------------------------------------------------------------------
// Build doubled/transposed bf16 weight matrices (unchanged).
// ---------------------------------------------------------------------------
__global__ __launch_bounds__(256, 2) void prep_w(
    const float* __restrict__ wq_r, const float* __restrict__ wq_i,
    const float* __restrict__ wkv_r, const float* __restrict__ wkv_i,
    const float* __restrict__ wo_r, const float* __restrict__ wo_i,
    u16* __restrict__ Wbig, u16* __restrict__ WoT)
{
    const long base = ((long)blockIdx.x * 256 + threadIdx.x) * 4;
    if (base < 786432) {
        const int c = (int)(base >> 9);
        const int k = (int)(base & 511);
        const int g = c >> 8, d = c & 255;
        const bool hi = k >= 256;
        const int k2 = hi ? k - 256 : k;
        const float* src;
        float sgn = 1.f;
        int col, stride;
        if (g < 2) {
            stride = 256; col = d;
            if (g == 0) { src = hi ? wq_i : wq_r; if (hi) sgn = -1.f; }
            else        { src = hi ? wq_r : wq_i; }
            sgn *= kQScaleL2;
        } else {
            stride = 512;
            col = (g >= 4) ? d + 256 : d;
            if ((g & 1) == 0) { src = hi ? wkv_i : wkv_r; if (hi) sgn = -1.f; }
            else              { src = hi ? wkv_r : wkv_i; }
        }
        short4v v;
        #pragma unroll
        for (int j = 0; j < 4; ++j)
            v[j] = (short)bf16b(src[(long)(k2 + j) * stride + col] * sgn);
        *(short4v*)(Wbig + base) = v;
    } else {
        const long o = base - 786432;
        const int c = (int)(o >> 9);
        const int k = (int)(o & 511);
        const bool hi = k >= 256;
        const int k2 = hi ? k - 256 : k;
        const float* src;
        float sgn = 1.f;
        int col;
        if (c < 256) { col = c;       src = hi ? wo_i : wo_r; if (hi) sgn = -1.f; }
        else         { col = c - 256; src = hi ? wo_r : wo_i; }
        short4v v;
        #pragma unroll
        for (int j = 0; j < 4; ++j)
            v[j] = (short)bf16b(src[(long)(k2 + j) * 256 + col] * sgn);
        *(short4v*)(WoT + o) = v;
    }
}

// ---------------------------------------------------------------------------
// QKV projection GEMM. v outputs stored TRANSPOSED per head:
// vrT/viT [bh][32 d][2048 n] so attention can stage V with b128 loads.
// ---------------------------------------------------------------------------
__global__ __launch_bounds__(256, 2) void gemm_proj(
    const float* __restrict__ xr_g, const float* __restrict__ xi_g,
    const u16* __restrict__ BT,
    u16* __restrict__ qr, u16* __restrict__ qi, u16* __restrict__ kr,
    u16* __restrict__ ki, u16* __restrict__ vrT, u16* __restrict__ viT)
{
    __shared__ __align__(16) u16 sA[128 * 32];
    __shared__ __align__(16) u16 sB[128 * 32];
    const int tid = threadIdx.x;
    const int lane = tid & 63, l31 = lane & 31, lh = lane >> 5;
    const int w = tid >> 6, wrow = w & 1, wcol = w >> 1;
    const int srow = tid >> 2, sseg = tid & 3;
    const int n0 = blockIdx.x * 128, m0 = blockIdx.y * 128;

    floatx16 a00 = {0}, a01 = {0}, a10 = {0}, a11 = {0};

    for (int kt = 0; kt < 512; kt += 32) {
        __syncthreads();
        const float* xbase = (kt < 256) ? xr_g : xi_g;
        const int kc = (kt & 255) + sseg * 8;
        #pragma unroll
        for (int i = 0; i < 2; ++i) {
            const int r = srow + i * 64;
            {
                const float* src = xbase + (long)(m0 + r) * 256 + kc;
                const float4 f0 = *(const float4*)(src);
                const float4 f1 = *(const float4*)(src + 4);
                short8 v;
                v[0] = (short)bf16b(f0.x); v[1] = (short)bf16b(f0.y);
                v[2] = (short)bf16b(f0.z); v[3] = (short)bf16b(f0.w);
                v[4] = (short)bf16b(f1.x); v[5] = (short)bf16b(f1.y);
                v[6] = (short)bf16b(f1.z); v[7] = (short)bf16b(f1.w);
                *(short8*)(sA + r * 32 + sseg * 8) = v;
            }
            *(short8*)(sB + r * 32 + sseg * 8) =
                *(const short8*)(BT + (long)(n0 + r) * 512 + kt + sseg * 8);
        }
        __syncthreads();
        #pragma unroll
        for (int s = 0; s < 2; ++s) {
            const int ko = s * 16 + lh * 8;
            const short8 fa0 = *(const short8*)(sA + (wrow * 64 + l31) * 32 + ko);
            const short8 fa1 = *(const short8*)(sA + (wrow * 64 + 32 + l31) * 32 + ko);
            const short8 fb0 = *(const short8*)(sB + (wcol * 64 + l31) * 32 + ko);
            const short8 fb1 = *(const short8*)(sB + (wcol * 64 + 32 + l31) * 32 + ko);
            a00 = MFMA_BF16(fa0, fb0, a00);
            a01 = MFMA_BF16(fa0, fb1, a01);
            a10 = MFMA_BF16(fa1, fb0, a10);
            a11 = MFMA_BF16(fa1, fb1, a11);
        }
    }

    floatx16 accs[2][2] = {{a00, a01}, {a10, a11}};
    #pragma unroll
    for (int rt = 0; rt < 2; ++rt) {
        #pragma unroll
        for (int ct = 0; ct < 2; ++ct) {
            const int colb = n0 + wcol * 64 + ct * 32;
            const int g = colb >> 8;
            const int h = (colb & 255) >> 5;
            if (g < 4) {
                u16* pl = (g == 0) ? qr : (g == 1) ? qi : (g == 2) ? kr : ki;
                #pragma unroll
                for (int reg = 0; reg < 16; ++reg) {
                    const int row = m0 + wrow * 64 + rt * 32 + (reg & 3) + 8 * (reg >> 2) + 4 * lh;
                    const int b = row >> 11, nn = row & 2047;
                    pl[(((long)(b * 8 + h)) * 2048 + nn) * 32 + l31] = bf16b(accs[rt][ct][reg]);
                }
            } else {
                u16* pl = (g == 4) ? vrT : viT;
                #pragma unroll
                for (int reg = 0; reg < 16; ++reg) {
                    const int row = m0 + wrow * 64 + rt * 32 + (reg & 3) + 8 * (reg >> 2) + 4 * lh;
                    const int b = row >> 11, nn = row & 2047;
                    pl[(((long)(b * 8 + h)) * 32 + l31) * 2048 + nn] = bf16b(accs[rt][ct][reg]);
                }
            }
        }
    }
}

// Build PV B-frag (bf16) for one 16-key step from 8 exp regs (keys g0: j+4lh,
// g1: 8+j+4lh). Cross-half exchange via shfl_xor(32) + select.
__device__ inline short8 mk_frag(const float* e, int lh) {
    float lo[4], hi[4];
    #pragma unroll
    for (int j = 0; j < 4; ++j) {
        const float a = e[j], b = e[4 + j];
        const float ax = __shfl_xor(a, 32);
        const float bx = __shfl_xor(b, 32);
        lo[j] = lh ? bx : a;
        hi[j] = lh ? b : ax;
    }
    union { unsigned u[4]; short8 s; } c;
    c.u[0] = pack2(lo[0], lo[1]);
    c.u[1] = pack2(lo[2], lo[3]);
    c.u[2] = pack2(hi[0], hi[1]);
    c.u[3] = pack2(hi[2], hi[3]);
    return c.s;
}

// ---------------------------------------------------------------------------
// MFMA flash attention, transposed-score formulation.
// S^T = K.Q^T  (C-layout: lane = query column, regs = key rows)
// U^T = V^T.P^T (P^T B-frags built in registers; no P LDS round-trip)
// Double-buffered K/V staging, 1 barrier per 32-key tile.
// ---------------------------------------------------------------------------
__global__ __launch_bounds__(256, 2) void attn_kernel(
    const u16* __restrict__ qr_g, const u16* __restrict__ qi_g,
    const u16* __restrict__ kr_g, const u16* __restrict__ ki_g,
    const u16* __restrict__ vrT_g, const u16* __restrict__ viT_g,
    u16* __restrict__ xo)
{
    __shared__ __align__(16) u16 smem[2][2][64 * 40];   // [K/V][buf] 20.0 KiB

    const int tid = threadIdx.x;
    const int lane = tid & 63, l31 = lane & 31, lh = lane >> 5;
    const int w = tid >> 6, strip = w & 1, qtype = w >> 1;
    const int bh = blockIdx.x;          // bh-major: per-XCD L2 locality
    const int i0 = blockIdx.y * 64;
    const long base = (long)bh * kN * kDH;

    // Q B-frags (B-layout: lane holds col=query=l31, k = d)
    const u16* qg = (qtype ? qi_g : qr_g) + base;
    short8 qB0, qB1;
    {
        const u16* qp = qg + (long)(i0 + strip * 32 + l31) * kDH;
        qB0 = *(const short8*)(qp + lh * 8);
        qB1 = *(const short8*)(qp + 16 + lh * 8);
    }

    // staging roles: one b128 per thread for K and V
    const int srow = tid & 63;   // K: bigkey row | V: vcol row
    const int sseg = tid >> 6;   // 8-elem segment
    const u16* kptr = ((srow < 32) ? kr_g : ki_g) + base
                    + (long)(srow & 31) * kDH + sseg * 8;
    const u16* vptr = ((srow < 32) ? vrT_g : viT_g)
                    + ((long)bh * 32 + (srow & 31)) * kN + sseg * 8;

    short8 kreg = *(const short8*)kptr;
    short8 vreg = *(const short8*)vptr;

    floatx16 U0r = {0}, U0i = {0}, U1r = {0}, U1i = {0};
    float La0 = 0.f, La1 = 0.f;

    for (int t = 0; t < 64; ++t) {
        u16* bK = smem[0][t & 1];
        u16* bV = smem[1][t & 1];
        *(short8*)(bK + srow * 40 + sseg * 8) = kreg;
        *(short8*)(bV + srow * 40 + sseg * 8) = vreg;
        __syncthreads();
        if (t < 63) {
            // K layout [bh][n][dh]: one 32-key tile = 32*32 = 1024 elems.
            kreg = *(const short8*)(kptr + (long)(t + 1) * 1024);
            // vT layout [d][n]: one 32-key tile = 32 elems along n.
            vreg = *(const short8*)(vptr + (t + 1) * 32);
        }

        // S^T: A = K rows (kr: 0..31, ki: 32..63), B = Q
        const short8 ka0 = *(const short8*)(bK + l31 * 40 + lh * 8);
        const short8 ka1 = *(const short8*)(bK + l31 * 40 + 16 + lh * 8);
        const short8 kb0 = *(const short8*)(bK + (32 + l31) * 40 + lh * 8);
        const short8 kb1 = *(const short8*)(bK + (32 + l31) * 40 + 16 + lh * 8);
        floatx16 S0 = {0}, S1 = {0};
        S0 = MFMA_BF16(ka0, qB0, S0);
        S0 = MFMA_BF16(ka1, qB1, S0);
        S1 = MFMA_BF16(kb0, qB0, S1);
        S1 = MFMA_BF16(kb1, qB1, S1);

        float e0[16], e1[16];
        #pragma unroll
        for (int r = 0; r < 16; ++r) {
            e0[r] = __builtin_amdgcn_exp2f(S0[r]);
            e1[r] = __builtin_amdgcn_exp2f(S1[r]);
            La0 += e0[r];
            La1 += e1[r];
        }

        // V^T A-frags (vr rows 0..31, vi rows 32..63)
        const short8 va0 = *(const short8*)(bV + l31 * 40 + lh * 8);
        const short8 va1 = *(const short8*)(bV + l31 * 40 + 16 + lh * 8);
        const short8 vb0 = *(const short8*)(bV + (32 + l31) * 40 + lh * 8);
        const short8 vb1 = *(const short8*)(bV + (32 + l31) * 40 + 16 + lh * 8);

        // PV: U^T += V^T . P^T, two 16-key steps
        {
            const short8 f00 = mk_frag(&e0[0], lh);
            const short8 f10 = mk_frag(&e1[0], lh);
            U0r = MFMA_BF16(va0, f00, U0r);
            U0i = MFMA_BF16(vb0, f00, U0i);
            U1r = MFMA_BF16(va0, f10, U1r);
            U1i = MFMA_BF16(vb0, f10, U1i);
            const short8 f01 = mk_frag(&e0[8], lh);
            const short8 f11 = mk_frag(&e1[8], lh);
            U0r = MFMA_BF16(va1, f01, U0r);
            U0i = MFMA_BF16(vb1, f01, U0i);
            U1r = MFMA_BF16(va1, f11, U1r);
            U1i = MFMA_BF16(vb1, f11, U1i);
        }
    }

    La0 += __shfl_xor(La0, 32);
    La1 += __shfl_xor(La1, 32);
    const float iL0 = 1.f / La0, iL1 = 1.f / La1;

    float po_r[16], po_i[16];
    #pragma unroll
    for (int r = 0; r < 16; ++r) {
        if (qtype == 0) {
            po_r[r] =  U0r[r] * iL0 - U1i[r] * iL1;
            po_i[r] =  U0i[r] * iL0 + U1r[r] * iL1;
        } else {
            po_r[r] = -U0i[r] * iL0 - U1r[r] * iL1;
            po_i[r] =  U0r[r] * iL0 - U1i[r] * iL1;
        }
    }

    __syncthreads();   // done with K/V buffers; overlay combine scratch
    float* sC = (float*)smem;   // [strip][2][32 d][33]
    if (qtype == 1) {
        float* dst = sC + strip * (2 * 32 * 33);
        #pragma unroll
        for (int r = 0; r < 16; ++r) {
            const int d = (r & 3) + 8 * (r >> 2) + 4 * lh;
            dst[d * 33 + l31] = po_r[r];
            dst[32 * 33 + d * 33 + l31] = po_i[r];
        }
    }
    __syncthreads();
    if (qtype == 0) {
        const float* src = sC + strip * (2 * 32 * 33);
        const int b = bh >> 3, h = bh & 7;
        u16* xrow = xo + ((long)(b * 2048 + i0 + strip * 32 + l31)) * 512 + h * 32;
        #pragma unroll
        for (int g = 0; g < 4; ++g) {
            const int d0 = 8 * g + 4 * lh;
            union { unsigned u[2]; uint2 v; } pr, pi;
            pr.u[0] = pack2(po_r[4 * g + 0] + src[(d0 + 0) * 33 + l31],
                            po_r[4 * g + 1] + src[(d0 + 1) * 33 + l31]);
            pr.u[1] = pack2(po_r[4 * g + 2] + src[(d0 + 2) * 33 + l31],
                            po_r[4 * g + 3] + src[(d0 + 3) * 33 + l31]);
            pi.u[0] = pack2(po_i[4 * g + 0] + src[32 * 33 + (d0 + 0) * 33 + l31],
                            po_i[4 * g + 1] + src[32 * 33 + (d0 + 1) * 33 + l31]);
            pi.u[1] = pack2(po_i[4 * g + 2] + src[32 * 33 + (d0 + 2) * 33 + l31],
                            po_i[4 * g + 3] + src[32 * 33 + (d0 + 3) * 33 + l31]);
            *(uint2*)(xrow + d0) = pr.v;
            *(uint2*)(xrow + 256 + d0) = pi.v;
        }
    }
}

// ---------------------------------------------------------------------------
// Output projection GEMM (unchanged).
// ---------------------------------------------------------------------------
__global__ __launch_bounds__(256, 2) void gemm_oproj(
    const u16* __restrict__ Xo, const u16* __restrict__ BT, float* __restrict__ out)
{
    __shared__ __align__(16) u16 sA[128 * 32];
    __shared__ __align__(16) u16 sB[128 * 32];
    const int tid = threadIdx.x;
    const int lane = tid & 63, l31 = lane & 31, lh = lane >> 5;
    const int w = tid >> 6, wrow = w & 1, wcol = w >> 1;
    const int srow = tid >> 2, sseg = tid & 3;
    const int n0 = blockIdx.x * 128, m0 = blockIdx.y * 128;

    floatx16 a00 = {0}, a01 = {0}, a10 = {0}, a11 = {0};

    for (int kt = 0; kt < 512; kt += 32) {
        __syncthreads();
        #pragma unroll
        for (int i = 0; i < 2; ++i) {
            const int r = srow + i * 64;
            *(short8*)(sA + r * 32 + sseg * 8) =
                *(const short8*)(Xo + (long)(m0 + r) * 512 + kt + sseg * 8);
            *(short8*)(sB + r * 32 + sseg * 8) =
                *(const short8*)(BT + (long)(n0 + r) * 512 + kt + sseg * 8);
        }
        __syncthreads();
        #pragma unroll
        for (int s = 0; s < 2; ++s) {
            const int ko = s * 16 + lh * 8;
            const short8 fa0 = *(const short8*)(sA + (wrow * 64 + l31) * 32 + ko);
            const short8 fa1 = *(const short8*)(sA + (wrow * 64 + 32 + l31) * 32 + ko);
            const short8 fb0 = *(const short8*)(sB + (wcol * 64 + l31) * 32 + ko);
            const short8 fb1 = *(const short8*)(sB + (wcol * 64 + 32 + l31) * 32 + ko);
            a00 = MFMA_BF16(fa0, fb0, a00);
            a01 = MFMA_BF16(fa0, fb1, a01);
            a10 = MFMA_BF16(fa1, fb0, a10);
            a11 = MFMA_BF16(fa1, fb1, a11);
        }
    }

    floatx16 accs[2][2] = {{a00, a01}, {a10, a11}};
    #pragma unroll
    for (int rt = 0; rt < 2; ++rt) {
        #pragma unroll
        for (int ct = 0; ct < 2; ++ct) {
            const int colb = n0 + wcol * 64 + ct * 32;
            #pragma unroll
            for (int reg = 0; reg < 16; ++reg) {
                const int row = m0 + wrow * 64 + rt * 32 + (reg & 3) + 8 * (reg >> 2) + 4 * lh;
                const int col = colb + l31;
                const float val = accs[rt][ct][reg];
                if (colb < 256) out[(long)row * 512 + col * 2] = val;
                else            out[(long)row * 512 + (col - 256) * 2 + 1] = val;
            }
        }
    }
}

extern "C" void kernel_launch(void* const* d_in, const int* in_sizes, int n_in,
                              void* d_out, int out_size, void* d_ws, size_t ws_size,
                              hipStream_t stream) {
    const float* xr    = (const float*)d_in[0];
    const float* xi    = (const float*)d_in[1];
    const float* wq_r  = (const float*)d_in[2];
    const float* wq_i  = (const float*)d_in[3];
    const float* wkv_r = (const float*)d_in[4];
    const float* wkv_i = (const float*)d_in[5];
    const float* wo_r  = (const float*)d_in[6];
    const float* wo_i  = (const float*)d_in[7];
    float* out = (float*)d_out;

    u16* ws16 = (u16*)d_ws;
    u16* qr   = ws16 + 0 * kPlane;
    u16* qi   = ws16 + 1 * kPlane;
    u16* kr   = ws16 + 2 * kPlane;
    u16* ki   = ws16 + 3 * kPlane;
    u16* vrT  = ws16 + 4 * kPlane;
    u16* viT  = ws16 + 5 * kPlane;
    u16* xo   = ws16 + 6 * kPlane;               // 2,097,152 elems
    u16* Wbig = ws16 + 8 * kPlane;               // 786,432 elems
    u16* WoT  = Wbig + 786432;                   // 262,144 elems

    prep_w<<<1024, 256, 0, stream>>>(wq_r, wq_i, wkv_r, wkv_i, wo_r, wo_i, Wbig, WoT);
    gemm_proj<<<dim3(12, 32), 256, 0, stream>>>(xr, xi, Wbig, qr, qi, kr, ki, vrT, viT);
    attn_kernel<<<dim3(kBH, kN / 64), 256, 0, stream>>>(qr, qi, kr, ki, vrT, viT, xo);
    gemm_oproj<<<dim3(4, 32), 256, 0, stream>>>(xo, WoT, out);
}